// Round 13
// baseline (2012.534 us; speedup 1.0000x reference)
//
#include <hip/hip_runtime.h>
#include <cstdint>
#include <cstddef>

// Mixtral MoE decode: E=8, B=32, H=4096, F=14336.
// I/O MODEL (solved r0-r12): device buffers are f32-upcast bf16; comparison
// truncates each f32 to its high 16 bits (bf16). Inputs read as float*,
// outputs written as bf16-RNE-rounded values stored in f32.
// MATH MODEL: np ref emulates bf16 at op boundaries (f32 accumulate -> RNE
// bf16 per einsum/elementwise op). Sparse top-2 execution, weights post-w2.

#define E_ 8
#define B_ 32
#define H_ 4096
#define F_ 14336
#define KC 128
#define KCP 132  // padded LDS row

typedef __attribute__((ext_vector_type(4))) float f32x4;

__device__ __forceinline__ float bfr(float f) {   // f32 -> bf16 value (RNE)
  unsigned int u; __builtin_memcpy(&u, &f, 4);
  u += 0x7fffu + ((u >> 16) & 1u);
  u &= 0xffff0000u;
  float r; __builtin_memcpy(&r, &u, 4); return r;
}

// ---------------------------------------------------- gate 1: logits --------
__global__ __launch_bounds__(256) void k_gate(const float* __restrict__ x,
                                              const float* __restrict__ gw,
                                              float* __restrict__ logits) {
  const int t = blockIdx.x;
  const int tid = threadIdx.x;
  const int e = tid & 7, part = tid >> 3;
  __shared__ float lp[32][8];
  const float* xr = x + (size_t)t * H_;
  float s = 0.f;
  for (int j = 0; j < 128; ++j) {
    const int k = part * 128 + j;
    s += xr[k] * gw[k * 8 + e];
  }
  lp[part][e] = s;
  __syncthreads();
  if (tid < 8) {
    float acc = 0.f;
    for (int p = 0; p < 32; ++p) acc += lp[p][tid];
    logits[t * 8 + tid] = bfr(acc);   // einsum output cast to bf16
  }
}

// ---------- gate 2: bf16 top-2 chain (multi-hot ties) + dense + lists -------
__global__ __launch_bounds__(64) void k_lists(const float* __restrict__ logits,
                                              float* __restrict__ wtsD,
                                              int* __restrict__ cnt,
                                              int* __restrict__ tok) {
  const int tid = threadIdx.x;
  __shared__ float w[32][8];
  if (tid < 32) {
    const float NEG = -__builtin_inff();  // bf16(f32.min) rounds to -inf
    float lg[8];
#pragma unroll
    for (int i = 0; i < 8; ++i) lg[i] = logits[tid * 8 + i];
    float m0 = NEG;
#pragma unroll
    for (int i = 0; i < 8; ++i) m0 = fmaxf(m0, lg[i]);
    float m1 = NEG;
#pragma unroll
    for (int i = 0; i < 8; ++i) m1 = fmaxf(m1, (lg[i] == m0) ? NEG : lg[i]);
    const float d  = bfr(m1 - m0);       // bf16 subtract
    const float ex = bfr(expf(d));       // bf16 exp
    const float s1 = bfr(1.f + ex);      // bf16 add
    const float wt = bfr(1.f / s1);      // bf16 reciprocal
    const float om = bfr(1.f - wt);      // bf16 (1 - w)
#pragma unroll
    for (int i = 0; i < 8; ++i) {
      float v = 0.f;
      if (lg[i] == m0) v += wt;          // multi-hot on exact bf16 ties
      if (lg[i] == m1) v += om;
      w[tid][i] = bfr(v);
    }
  }
  __syncthreads();
  if (tid < 8) {
    int c = 0;
    for (int t = 0; t < 32; ++t) {
      const float v = w[t][tid];
      wtsD[t * 8 + tid] = v;             // dense weights for the final mix
      if (v != 0.f) { tok[tid * 32 + c] = t; ++c; }
    }
    cnt[tid] = c;
    for (int j = c; j < 32; ++j) tok[tid * 32 + j] = 0;
  }
}

// ------------- ffn13: inter[e][j][f] = bf16(silu-chain), j<cnt[e] -----------
__global__ __launch_bounds__(256) void k_ffn13(const float* __restrict__ x,
                                               const float* __restrict__ w1,
                                               const float* __restrict__ w3,
                                               const int* __restrict__ cnt,
                                               const int* __restrict__ tok,
                                               float* __restrict__ inter) {
  const int e = blockIdx.y;
  const int tid = threadIdx.x;
  const int f = blockIdx.x * 256 + tid;
  const float* W1 = w1 + (size_t)e * H_ * F_ + f;
  const float* W3 = w3 + (size_t)e * H_ * F_ + f;
  const int cn = cnt[e];
  const int nch = (cn + 7) >> 3;

  __shared__ __attribute__((aligned(16))) float xs[32][KCP];
  __shared__ int stok[32];
  if (tid < 32) stok[tid] = tok[e * 32 + tid];

  float acc1[32], acc3[32];
#pragma unroll
  for (int j = 0; j < 32; ++j) { acc1[j] = 0.f; acc3[j] = 0.f; }

  const int j = tid >> 3, kk0 = (tid & 7) * 16;

#pragma unroll 1
  for (int k0 = 0; k0 < H_; k0 += KC) {
    __syncthreads();
    if (j < cn) {
      const float* xr = x + (size_t)stok[j] * H_ + k0 + kk0;
#pragma unroll
      for (int q = 0; q < 4; ++q)
        *(f32x4*)&xs[j][kk0 + q * 4] = *(const f32x4*)(xr + q * 4);
    } else {
#pragma unroll
      for (int q = 0; q < 16; ++q) xs[j][kk0 + q] = 0.f;  // keep acc finite
    }
    __syncthreads();

#pragma unroll 1
    for (int kk = 0; kk < KC; kk += 4) {
      float wv1[4], wv3[4];
#pragma unroll
      for (int u = 0; u < 4; ++u) {
        wv1[u] = W1[(size_t)(k0 + kk + u) * F_];
        wv3[u] = W3[(size_t)(k0 + kk + u) * F_];
      }
#pragma unroll
      for (int c = 0; c < 4; ++c) {
        if (c < nch) {
#pragma unroll
          for (int t8 = 0; t8 < 8; ++t8) {
            const int j2 = c * 8 + t8;
            const f32x4 xv = *(const f32x4*)&xs[j2][kk];
#pragma unroll
            for (int u = 0; u < 4; ++u) {
              acc1[j2] += xv[u] * wv1[u];
              acc3[j2] += xv[u] * wv3[u];
            }
          }
        }
      }
    }
  }

  float* ip = inter + (size_t)e * 32 * F_ + f;
#pragma unroll
  for (int jj = 0; jj < 32; ++jj) {
    if (jj < cn) {
      const float hb = bfr(acc1[jj]);                 // h: bf16 einsum out
      const float gb = bfr(acc3[jj]);                 // g: bf16 einsum out
      const float sg = bfr(1.f / (1.f + expf(-hb)));  // sigmoid -> bf16
      const float sl = bfr(hb * sg);                  // silu mul -> bf16
      ip[(size_t)jj * F_] = bfr(sl * gb);             // product -> bf16
    }
  }
}

// --------------------- ffn2: partial[(e,fs)][tok[j]][h] = inter @ w2 --------
__global__ __launch_bounds__(256) void k_ffn2(const float* __restrict__ inter,
                                              const float* __restrict__ w2,
                                              const int* __restrict__ cnt,
                                              const int* __restrict__ tok,
                                              float* __restrict__ partial) {
  const int e = blockIdx.y;
  const int fs = blockIdx.z;
  const int tid = threadIdx.x;
  const int h = blockIdx.x * 256 + tid;
  const float* W2 = w2 + (size_t)e * F_ * H_ + h;
  const int cn = cnt[e];
  const int nch = (cn + 7) >> 3;
  const int base_f = fs * (F_ / 4);

  __shared__ __attribute__((aligned(16))) float xs[32][KCP];
  __shared__ int stok[32];
  if (tid < 32) stok[tid] = tok[e * 32 + tid];

  float acc[32];
#pragma unroll
  for (int j = 0; j < 32; ++j) acc[j] = 0.f;

  const int j = tid >> 3, kk0 = (tid & 7) * 16;

#pragma unroll 1
  for (int f0 = 0; f0 < F_ / 4; f0 += KC) {
    __syncthreads();
    if (j < cn) {
      const float* ir = inter + ((size_t)e * 32 + j) * F_ + base_f + f0 + kk0;
#pragma unroll
      for (int q = 0; q < 4; ++q)
        *(f32x4*)&xs[j][kk0 + q * 4] = *(const f32x4*)(ir + q * 4);
    } else {
#pragma unroll
      for (int q = 0; q < 16; ++q) xs[j][kk0 + q] = 0.f;
    }
    __syncthreads();

#pragma unroll 1
    for (int kk = 0; kk < KC; kk += 4) {
      float wv[4];
#pragma unroll
      for (int u = 0; u < 4; ++u)
        wv[u] = W2[(size_t)(base_f + f0 + kk + u) * H_];
#pragma unroll
      for (int c = 0; c < 4; ++c) {
        if (c < nch) {
#pragma unroll
          for (int t8 = 0; t8 < 8; ++t8) {
            const int j2 = c * 8 + t8;
            const f32x4 xv = *(const f32x4*)&xs[j2][kk];
#pragma unroll
            for (int u = 0; u < 4; ++u) acc[j2] += xv[u] * wv[u];
          }
        }
      }
    }
  }

  float* ps = partial + (size_t)(e * 4 + fs) * (B_ * H_) + h;
#pragma unroll
  for (int jj = 0; jj < 32; ++jj) {
    if (jj < cn) ps[(size_t)stok[jj] * H_] = acc[jj];  // others stay memset-0
  }
}

// ---- reduce: eo = bf16(sum_fs); out = bf16( sum_e eo * wtsD ) --------------
__global__ __launch_bounds__(256) void k_reduce(const float* __restrict__ partial,
                                                const float* __restrict__ wtsD,
                                                float* __restrict__ out) {
  const int n = blockIdx.x * 256 + threadIdx.x;  // 131072
  const int t = n >> 12;
  float s = 0.f;
#pragma unroll
  for (int e = 0; e < 8; ++e) {
    float eo = 0.f;
#pragma unroll
    for (int fs = 0; fs < 4; ++fs)
      eo += partial[(size_t)(e * 4 + fs) * (B_ * H_) + n];
    s += bfr(eo) * wtsD[t * 8 + e];   // expert_out cast to bf16, then f32 mix
  }
  out[n] = bfr(s);   // final bf16 value, stored as f32 (truncate-safe)
}

// ---------------------------------------------------------------------------
extern "C" void kernel_launch(void* const* d_in, const int* in_sizes, int n_in,
                              void* d_out, int out_size, void* d_ws, size_t ws_size,
                              hipStream_t stream) {
  const float* x  = (const float*)d_in[0];
  const float* gw = (const float*)d_in[1];
  const float* w1 = (const float*)d_in[2];   // (E,H,F), dict order
  const float* w3 = (const float*)d_in[3];   // (E,H,F)
  const float* w2 = (const float*)d_in[4];   // (E,F,H)
  float* out = (float*)d_out;

  char* ws = (char*)d_ws;
  float* logits  = (float*)ws;                    // 1 KB
  float* wtsD    = (float*)(ws + 2048);           // 1 KB
  int*   cnt     = (int*)(ws + 4096);             // 32 B
  int*   tok     = (int*)(ws + 6144);             // 1 KB
  float* inter   = (float*)(ws + 16384);          // E*B*F*4 = 14,680,064 B
  float* partial = (float*)(ws + 16384 + (size_t)E_ * B_ * F_ * 4);  // 16 MB

  hipLaunchKernelGGL(k_gate, dim3(32), dim3(256), 0, stream, x, gw, logits);
  hipLaunchKernelGGL(k_lists, dim3(1), dim3(64), 0, stream, logits, wtsD, cnt, tok);
  hipMemsetAsync(partial, 0, (size_t)32 * B_ * H_ * sizeof(float), stream);
  hipLaunchKernelGGL(k_ffn13, dim3(56, 8), dim3(256), 0, stream,
                     x, w1, w3, cnt, tok, inter);
  hipLaunchKernelGGL(k_ffn2, dim3(16, 8, 4), dim3(256), 0, stream,
                     inter, w2, cnt, tok, partial);
  hipLaunchKernelGGL(k_reduce, dim3(512), dim3(256), 0, stream, partial, wtsD, out);
}